// Round 6
// baseline (81.836 us; speedup 1.0000x reference)
//
#include <hip/hip_runtime.h>
#include <hip/hip_bf16.h>
#include <stdint.h>

#define GAMMA 1e-4f

typedef int i32x4 __attribute__((ext_vector_type(4)));
typedef int i32x8 __attribute__((ext_vector_type(8)));
typedef float f32x16 __attribute__((ext_vector_type(16)));

__device__ __forceinline__ float bf2f(unsigned short u) {
  unsigned int x = ((unsigned int)u) << 16;
  float f; __builtin_memcpy(&f, &x, 4);
  return f;
}

// bit-exact float -> OCP e4m3fn (RNE, satfinite).
__device__ __forceinline__ unsigned char f2e4m3(float x) {
  float a = fabsf(x);
  unsigned char s = x < 0.f ? 0x80 : 0;
  a = fminf(a, 448.f);
  if (a < 0.015625f) {                    // subnormal region, ulp 2^-9
    int q = (int)rintf(a * 512.f);
    return s | (unsigned char)q;
  }
  unsigned int u; __builtin_memcpy(&u, &a, 4);
  u += 0x7FFFFu + ((u >> 20) & 1);        // RNE to 3 mantissa bits
  u &= 0xFFF00000u;
  int e2 = (int)(u >> 23) - 127;
  unsigned int mant = (u >> 20) & 7;
  return s | (unsigned char)(((e2 + 7) << 3) | mant);
}

__device__ __forceinline__ unsigned int pack4(float a, float b, float c, float d) {
  return (unsigned)f2e4m3(a) | ((unsigned)f2e4m3(b) << 8) |
         ((unsigned)f2e4m3(c) << 16) | ((unsigned)f2e4m3(d) << 24);
}

// ---------------- Kernel 1: merged prep (fp8 outputs, fp32 norms) ----------------
__global__ __launch_bounds__(256) void prep_k(
    const float* __restrict__ x, const float* __restrict__ cw,
    const float* __restrict__ cb, unsigned char* __restrict__ fA8,
    float* __restrict__ f2, const float* __restrict__ pr,
    unsigned char* __restrict__ pB8, float* __restrict__ p2) {
  const int tid = threadIdx.x;
  __shared__ float red[4];
  if (blockIdx.x < 4096) {
    const int j = blockIdx.x;
    const float4* src = (const float4*)(pr + (size_t)j * 4096);
    float ssq = 0.f;
    unsigned int w4[4];
#pragma unroll
    for (int k = 0; k < 4; k++) {
      float4 v = src[tid * 4 + k];
      ssq += v.x * v.x + v.y * v.y + v.z * v.z + v.w * v.w;
      w4[k] = pack4(v.x, v.y, v.z, v.w);
    }
    *(uint4*)(pB8 + (size_t)j * 4096 + tid * 16) = make_uint4(w4[0], w4[1], w4[2], w4[3]);
    for (int off = 32; off > 0; off >>= 1) ssq += __shfl_down(ssq, off);
    if ((tid & 63) == 0) red[tid >> 6] = ssq;
    __syncthreads();
    if (tid == 0) p2[j] = red[0] + red[1] + red[2] + red[3];
  } else {
    const int b = blockIdx.x - 4096;
    __shared__ float swb[20];
    if (tid < 16) swb[tid] = cw[tid];
    else if (tid < 20) swb[tid] = cb[tid - 16];
    __syncthreads();
    float w[16], bias[4];
#pragma unroll
    for (int i = 0; i < 16; i++) w[i] = swb[i];
#pragma unroll
    for (int c = 0; c < 4; c++) bias[c] = swb[16 + c];
    const float* xb = x + (size_t)b * 4096;
    unsigned char* fb8 = fA8 + (size_t)b * 4096;
    const int p0 = tid * 4;
    const int h = p0 >> 5, w0 = p0 & 31;
    const float* r0 = xb + (2 * h) * 64 + 2 * w0;
    const float* r1 = r0 + 64;
    float4 a0 = *(const float4*)r0, a1 = *(const float4*)(r0 + 4);
    float4 c0 = *(const float4*)r1, c1 = *(const float4*)(r1 + 4);
    float ssq = 0.f;
#pragma unroll
    for (int c = 0; c < 4; c++) {
      float w00 = w[c * 4], w01 = w[c * 4 + 1], w10 = w[c * 4 + 2], w11 = w[c * 4 + 3];
      float v0 = bias[c] + a0.x * w00 + a0.y * w01 + c0.x * w10 + c0.y * w11;
      float v1 = bias[c] + a0.z * w00 + a0.w * w01 + c0.z * w10 + c0.w * w11;
      float v2 = bias[c] + a1.x * w00 + a1.y * w01 + c1.x * w10 + c1.y * w11;
      float v3 = bias[c] + a1.z * w00 + a1.w * w01 + c1.z * w10 + c1.w * w11;
      ssq += v0 * v0 + v1 * v1 + v2 * v2 + v3 * v3;
      *(unsigned int*)(fb8 + c * 1024 + p0) = pack4(v0, v1, v2, v3);
    }
    for (int off = 32; off > 0; off >>= 1) ssq += __shfl_down(ssq, off);
    if ((tid & 63) == 0) red[tid >> 6] = ssq;
    __syncthreads();
    if (tid == 0) f2[b] = red[0] + red[1] + red[2] + red[3];
  }
}

// ---------------- Kernel 2: fp8 GEMM, 32x32x64 MFMA, ring-4 frag-prefetch pipeline ----
// BM=128, BN=256, BK=64; 8 waves (2M x 4N), wave tile 64x64 (2x2 frags of 32).
// Ring-4 (96 KiB): publish-ahead-2 so frags(t+1) are ds_read during MFMAs(t).
// LDS per buffer: A [2 khalf][128 rows][32B] @0 (8KB), B [2][256][32B] @8192 (16KB).
// Swizzle: phys = logical ^ ((khalf&1)<<4) (bit12 for A, bit13 for B) -> 0 conflicts.
#define SWZA(o) ((o) ^ ((((o) >> 12) & 1) << 4))
#define SWZB(o) ((o) ^ ((((o) >> 13) & 1) << 4))
#define TILE_BYTES 24576

#define GLDS(gsrc, ldst)                                                    \
  __builtin_amdgcn_global_load_lds(                                         \
      (__attribute__((address_space(1))) void*)(void*)(gsrc),               \
      (__attribute__((address_space(3))) void*)(ldst), 16, 0, 0)

#define MFMA32(a, b, c)                                                     \
  __builtin_amdgcn_mfma_scale_f32_32x32x64_f8f6f4(                          \
      (a), (b), (c), 0, 0, 0, 0x7f7f7f7fu, 0, 0x7f7f7f7fu)

__device__ __forceinline__ i32x8 read32(const char* plo, const char* phi) {
  i32x8 r;
  *(i32x4*)&r = *(const i32x4*)plo;
  *(((i32x4*)&r) + 1) = *(const i32x4*)phi;
  return r;
}

// one K-tile: read frags(t+1) from PTN, stage tile(t+3) into PTS at K-byte KB,
// MFMA on CUR regs, counted waits, one barrier.
#define TBODY(PTN, PTS, CA0, CA1, CB0, CB1, NA0, NA1, NB0, NB1, KB)         \
  __builtin_amdgcn_sched_barrier(0);                                        \
  NA0 = read32((PTN) + arlo0, (PTN) + arhi0);                               \
  NA1 = read32((PTN) + arlo1, (PTN) + arhi1);                               \
  NB0 = read32((PTN) + brlo0, (PTN) + brhi0);                               \
  NB1 = read32((PTN) + brlo1, (PTN) + brhi1);                               \
  __builtin_amdgcn_sched_barrier(0);                                        \
  GLDS(agp + (KB), (PTS) + aoff);                                           \
  GLDS(bgp0 + (KB), (PTS) + 8192 + boff0);                                  \
  GLDS(bgp1 + (KB), (PTS) + 8192 + boff1);                                  \
  __builtin_amdgcn_sched_barrier(0);                                        \
  asm volatile("s_waitcnt lgkmcnt(8)" ::: "memory");                        \
  __builtin_amdgcn_sched_barrier(0);                                        \
  __builtin_amdgcn_s_setprio(1);                                            \
  acc00 = MFMA32(CA0, CB0, acc00);                                          \
  acc01 = MFMA32(CA0, CB1, acc01);                                          \
  acc10 = MFMA32(CA1, CB0, acc10);                                          \
  acc11 = MFMA32(CA1, CB1, acc11);                                          \
  __builtin_amdgcn_s_setprio(0);                                            \
  __builtin_amdgcn_sched_barrier(0);                                        \
  asm volatile("s_waitcnt vmcnt(3)" ::: "memory");                          \
  __builtin_amdgcn_sched_barrier(0);                                        \
  __builtin_amdgcn_s_barrier();

__global__ __launch_bounds__(512, 1) void gemm_kv_k(
    const unsigned char* __restrict__ A, const unsigned char* __restrict__ B,
    const float* __restrict__ f2, const float* __restrict__ p2,
    __hip_bfloat16* __restrict__ kv) {
  __shared__ __align__(16) char lds[4 * TILE_BYTES];  // 96 KiB
  const int tid = threadIdx.x;
  const int wave = tid >> 6, lane = tid & 63;
  const int h = lane >> 5, l32 = lane & 31;
  const int wr = wave >> 2, wc = wave & 3;

  // XCD-aware tile swizzle: 256 WGs = 8 XCDs x 32
  const int wg = blockIdx.x;
  const int xcd = wg & 7, loc = wg >> 3;
  const int bm = (xcd & 1) * 8 + (loc & 7);
  const int bn = (xcd >> 1) * 4 + (loc >> 3);

  // staging: linear LDS dest, inverse-swizzled global src (rule #21)
  const unsigned char* agp;
  const unsigned char* bgp0;
  const unsigned char* bgp1;
  int aoff, boff0, boff1;
  {
    int phys = tid * 16;                    // A region [0,8192)
    aoff = phys;
    int lg = SWZA(phys);
    agp = A + (size_t)(bm * 128 + ((lg & 4095) >> 5)) * 4096 + (lg >> 12) * 32 + (lg & 31);
  }
  {
    int phys = tid * 16;                    // B region [0,16384)
    boff0 = phys;
    int lg = SWZB(phys);
    bgp0 = B + (size_t)(bn * 256 + ((lg & 8191) >> 5)) * 4096 + (lg >> 13) * 32 + (lg & 31);
  }
  {
    int phys = (tid + 512) * 16;
    boff1 = phys;
    int lg = SWZB(phys);
    bgp1 = B + (size_t)(bn * 256 + ((lg & 8191) >> 5)) * 4096 + (lg >> 13) * 32 + (lg & 31);
  }

  // fragment read offsets: lane(row=l32, khalf=h) reads 32 consecutive K bytes
  const int lgA0 = h * 4096 + (wr * 64 + l32) * 32;
  const int lgA1 = h * 4096 + (wr * 64 + 32 + l32) * 32;
  const int lgB0 = h * 8192 + (wc * 64 + l32) * 32;
  const int lgB1 = h * 8192 + (wc * 64 + 32 + l32) * 32;
  const int arlo0 = SWZA(lgA0), arhi0 = SWZA(lgA0 + 16);
  const int arlo1 = SWZA(lgA1), arhi1 = SWZA(lgA1 + 16);
  const int brlo0 = 8192 + SWZB(lgB0), brhi0 = 8192 + SWZB(lgB0 + 16);
  const int brlo1 = 8192 + SWZB(lgB1), brhi1 = 8192 + SWZB(lgB1 + 16);

  f32x16 acc00 = {}, acc01 = {}, acc10 = {}, acc11 = {};
  i32x8 Xa0, Xa1, Xb0, Xb1, Ya0, Ya1, Yb0, Yb1;

  char* pt0 = lds;
  char* pt1 = lds + TILE_BYTES;
  char* pt2 = lds + 2 * TILE_BYTES;
  char* pt3 = lds + 3 * TILE_BYTES;

  // prologue: stage tiles 0,1,2 (K-tile stride = 64 bytes)
  GLDS(agp, pt0 + aoff);
  GLDS(bgp0, pt0 + 8192 + boff0);
  GLDS(bgp1, pt0 + 8192 + boff1);
  GLDS(agp + 64, pt1 + aoff);
  GLDS(bgp0 + 64, pt1 + 8192 + boff0);
  GLDS(bgp1 + 64, pt1 + 8192 + boff1);
  GLDS(agp + 128, pt2 + aoff);
  GLDS(bgp0 + 128, pt2 + 8192 + boff0);
  GLDS(bgp1 + 128, pt2 + 8192 + boff1);
  asm volatile("s_waitcnt vmcnt(3)" ::: "memory");  // tiles 0,1 landed
  __builtin_amdgcn_s_barrier();

  // initial fragments: tile 0 -> X
  Xa0 = read32(pt0 + arlo0, pt0 + arhi0);
  Xa1 = read32(pt0 + arlo1, pt0 + arhi1);
  Xb0 = read32(pt0 + brlo0, pt0 + brhi0);
  Xb1 = read32(pt0 + brlo1, pt0 + brhi1);

#pragma unroll 1
  for (int t = 0; t < 64; t += 2) {
    const int kb1 = ((t + 3) & 63) * 64;
    const int kb2 = ((t + 4) & 63) * 64;
    TBODY(pt1, pt3, Xa0, Xa1, Xb0, Xb1, Ya0, Ya1, Yb0, Yb1, kb1);
    TBODY(pt2, pt0, Ya0, Ya1, Yb0, Yb1, Xa0, Xa1, Xb0, Xb1, kb2);
    char* s0 = pt0; char* s1 = pt1;
    pt0 = pt2; pt1 = pt3; pt2 = s0; pt3 = s1;
  }

  asm volatile("s_waitcnt vmcnt(0) lgkmcnt(0)" ::: "memory");  // drain tail

  // epilogue: kv = bf16(exp(-gamma * max(f2 + p2 - 2*dot, 0)))
  // C/D 32x32 layout: col = lane&31, row = (reg&3) + 8*(reg>>2) + 4*(lane>>5)
  const int colb = bn * 256 + wc * 64 + l32;
  const float p2v0 = p2[colb];
  const float p2v1 = p2[colb + 32];

#define EPI(ACC0, ACC1, MOFF)                                               \
  {                                                                         \
    const int rb = bm * 128 + wr * 64 + (MOFF) + 4 * h;                     \
    _Pragma("unroll") for (int g = 0; g < 4; g++) {                         \
      _Pragma("unroll") for (int j = 0; j < 4; j++) {                       \
        const int grow = rb + j + 8 * g;                                    \
        const float f2v = f2[grow];                                         \
        __hip_bfloat16* kvp = kv + (size_t)grow * 4096 + colb;              \
        float d0 = fmaxf(f2v + p2v0 - 2.0f * ACC0[4 * g + j], 0.f);         \
        float d1 = fmaxf(f2v + p2v1 - 2.0f * ACC1[4 * g + j], 0.f);         \
        kvp[0] = __float2bfloat16(__expf(-GAMMA * d0));                     \
        kvp[32] = __float2bfloat16(__expf(-GAMMA * d1));                    \
      }                                                                     \
    }                                                                       \
  }
  EPI(acc00, acc01, 0)
  EPI(acc10, acc11, 32)
#undef EPI
}

// ---------------- Kernel 3: logits = kv @ head_w^T + b; log_softmax (4 rows/block) ----
__global__ __launch_bounds__(256) void head_ls_k(
    const __hip_bfloat16* __restrict__ kv, const float* __restrict__ hw,
    const float* __restrict__ hb, float* __restrict__ out) {
  const int bb = blockIdx.x * 4;
  const int tid = threadIdx.x;
  float part[4][10];
#pragma unroll
  for (int r = 0; r < 4; r++)
#pragma unroll
    for (int c = 0; c < 10; c++) part[r][c] = 0.f;
#pragma unroll
  for (int k = 0; k < 4; k++) {
    int idx = tid + k * 256;
    float4 w[10];
#pragma unroll
    for (int c = 0; c < 10; c++) w[c] = *(const float4*)(hw + c * 4096 + idx * 4);
#pragma unroll
    for (int r = 0; r < 4; r++) {
      ushort4 v = ((const ushort4*)(kv + (size_t)(bb + r) * 4096))[idx];
      float a0 = bf2f(v.x), a1 = bf2f(v.y), a2 = bf2f(v.z), a3 = bf2f(v.w);
#pragma unroll
      for (int c = 0; c < 10; c++)
        part[r][c] += a0 * w[c].x + a1 * w[c].y + a2 * w[c].z + a3 * w[c].w;
    }
  }
#pragma unroll
  for (int r = 0; r < 4; r++)
#pragma unroll
    for (int c = 0; c < 10; c++)
      for (int off = 32; off > 0; off >>= 1) part[r][c] += __shfl_down(part[r][c], off);
  __shared__ float red[4][4][10];
  if ((tid & 63) == 0) {
#pragma unroll
    for (int r = 0; r < 4; r++)
#pragma unroll
      for (int c = 0; c < 10; c++) red[tid >> 6][r][c] = part[r][c];
  }
  __syncthreads();
  if (tid < 4) {
    const int r = tid;
    float l[10], m = -1e30f;
#pragma unroll
    for (int c = 0; c < 10; c++) {
      l[c] = red[0][r][c] + red[1][r][c] + red[2][r][c] + red[3][r][c] + hb[c];
      m = fmaxf(m, l[c]);
    }
    float s = 0.f;
#pragma unroll
    for (int c = 0; c < 10; c++) s += __expf(l[c] - m);
    float lse = logf(s);
#pragma unroll
    for (int c = 0; c < 10; c++) out[(size_t)(bb + r) * 10 + c] = l[c] - m - lse;
  }
}

extern "C" void kernel_launch(void* const* d_in, const int* in_sizes, int n_in,
                              void* d_out, int out_size, void* d_ws, size_t ws_size,
                              hipStream_t stream) {
  const float* x      = (const float*)d_in[0];
  const float* protos = (const float*)d_in[1];
  const float* conv_w = (const float*)d_in[2];
  const float* conv_b = (const float*)d_in[3];
  const float* head_w = (const float*)d_in[4];
  const float* head_b = (const float*)d_in[5];
  float* out = (float*)d_out;
  char* ws = (char*)d_ws;

  unsigned char* pB8  = (unsigned char*)ws;                      // 4096x4096 fp8 = 16 MB
  unsigned char* fA8  = (unsigned char*)(ws + (16u << 20));      // 2048x4096 fp8 =  8 MB
  __hip_bfloat16* kvb = (__hip_bfloat16*)(ws + (24u << 20));     // 2048x4096 bf16 = 16 MB
  float* f2 = (float*)(ws + (40u << 20));                        // 2048 f32
  float* p2 = (float*)(ws + (40u << 20) + 8192);                 // 4096 f32

  hipLaunchKernelGGL(prep_k, dim3(6144), dim3(256), 0, stream,
                     x, conv_w, conv_b, fA8, f2, protos, pB8, p2);
  hipLaunchKernelGGL(gemm_kv_k, dim3(256), dim3(512), 0, stream, fA8, pB8, f2, p2, kvb);
  hipLaunchKernelGGL(head_ls_k, dim3(512), dim3(256), 0, stream, kvb, head_w, head_b, out);
}